// Round 10
// baseline (108.778 us; speedup 1.0000x reference)
//
#include <hip/hip_runtime.h>
#include <math.h>

#define NEG_INF (-INFINITY)

__device__ __forceinline__ float nll3(float l0, float l1, float l2) {
    float m = fmaxf(l0, fmaxf(l1, l2));
    float e0 = __expf(l0 - m);
    float e1 = __expf(l1 - m);
    float e2 = __expf(l2 - m);
    return __logf(e0 + e1 + e2) - (l0 - m);
}

// problem sizes
#define S0 262144          // 64^3
#define S1 32768           // 32^3
#define N0 (12 * S0)       // 3,145,728
#define N1 (12 * S1)       //   393,216
#define N0_4 (N0 / 4)      // 786,432
#define N1_4 (N1 / 4)      //  98,304
#define P1_BLOCKS ((N0_4 + N1_4) / 256)   // 3456

// ---------------------------------------------------------------------------
// Pass 1: pure streaming nll compute. One float4 per thread, fully coalesced
// sequential reads (3 class streams) + sequential write. All transcendentals
// happen here with massive TLP and no dependency chains.
// ---------------------------------------------------------------------------
__global__ __launch_bounds__(256)
void nll_pass(const float* __restrict__ logit0,
              const float* __restrict__ logit1,
              float* __restrict__ nllws) {
    const int idx = blockIdx.x * 256 + threadIdx.x;
    if (idx < N0_4) {
        const int per = S0 / 4;
        const int ba = idx / per, r4 = idx % per;
        const int a = ba % 3, b = ba / 3;
        const float* p = logit0 + ((long)b * 9 + a) * S0 + (long)r4 * 4;
        float4 l0 = *(const float4*)p;
        float4 l1 = *(const float4*)(p + (long)3 * S0);
        float4 l2 = *(const float4*)(p + (long)6 * S0);
        float4 o;
        o.x = nll3(l0.x, l1.x, l2.x);
        o.y = nll3(l0.y, l1.y, l2.y);
        o.z = nll3(l0.z, l1.z, l2.z);
        o.w = nll3(l0.w, l1.w, l2.w);
        *(float4*)(nllws + (long)ba * S0 + (long)r4 * 4) = o;
    } else {
        const int j = idx - N0_4;
        const int per = S1 / 4;
        const int ba = j / per, r4 = j % per;
        const int a = ba % 3, b = ba / 3;
        const float* p = logit1 + ((long)b * 9 + a) * S1 + (long)r4 * 4;
        float4 l0 = *(const float4*)p;
        float4 l1 = *(const float4*)(p + (long)3 * S1);
        float4 l2 = *(const float4*)(p + (long)6 * S1);
        float4 o;
        o.x = nll3(l0.x, l1.x, l2.x);
        o.y = nll3(l0.y, l1.y, l2.y);
        o.z = nll3(l0.z, l1.z, l2.z);
        o.w = nll3(l0.w, l1.w, l2.w);
        *(float4*)(nllws + N0 + (long)ba * S1 + (long)r4 * 4) = o;
    }
}

// ---------------------------------------------------------------------------
// Pass 2: NMS + focal weighting from the precomputed nll map.
// Wave-strip layout (LR = W/4 lanes/row, group g = input row h0-1+g).
// Mod-3 register pipeline WITHOUT copies: load into slot (s+2)%3, consume
// slot s%3 — the compiler cannot sink loads past a use 2 iterations later.
// 1 nll float4 + 1 pg float4 per lane per step; no transcendentals except
// the sparse __expf at emit. Tie rule compares stored vs stored — bit-exact.
// ---------------------------------------------------------------------------
template<int W, int NR, int TD, int D, int H>
__device__ void nms_strip(int uid, int lane,
                          const float* __restrict__ nlvl,
                          const float* __restrict__ pg,
                          float2* __restrict__ slot) {
    constexpr int LR = W / 4;
    constexpr int NI = NR + 2;
    constexpr int HG = H / NR;
    constexpr int DT = D / TD;
    const int q = lane % LR;
    const int g = lane / LR;

    int t = uid;
    const int hg = t % HG; t /= HG;
    const int dt = t % DT; t /= DT;
    const int ba = t;                   // b*3 + a
    const int h0 = hg * NR, d0 = dt * TD;
    const int HW = H * W;
    const long S = (long)D * HW;
    const float* nb  = nlvl + (long)ba * S;
    const float* pgb = pg + (long)ba * S;

    const int jrow = h0 - 1 + g;
    const bool hv = (jrow >= 0) && (jrow < H) && (g < NI);
    const int hcl = min(max(jrow, 0), H - 1);
    const int rowoff = hcl * W + 4 * q;
    const int prowoff = (h0 + min(g, NR - 1)) * W + 4 * q;

    float4 nl[3]; bool vd[3]; float4 pq[3];
    // prologue: planes d0-1 (slot 0), d0 (slot 1)
    nl[0] = *(const float4*)(nb + (long)max(d0 - 1, 0) * HW + rowoff);
    vd[0] = (d0 - 1 >= 0);
    nl[1] = *(const float4*)(nb + (long)d0 * HW + rowoff);
    vd[1] = true;
    nl[2] = make_float4(0.f, 0.f, 0.f, 0.f); vd[2] = false;
    pq[0] = pq[1] = pq[2] = make_float4(0.f, 0.f, 0.f, 0.f);

    float vm0[4], vm1[4], cc1[4];
#pragma unroll
    for (int i = 0; i < 4; ++i) { vm0[i] = NEG_INF; vm1[i] = NEG_INF; cc1[i] = 0.f; }

    float loss = 0.f, cnt = 0.f;

#pragma unroll
    for (int s = 0; s <= TD + 1; ++s) {
        // ---- depth-2 prefetch into rotating slots (no copies) ----
        if (s <= TD - 1) {                                // static guard
            const int pd = d0 + 1 + s;
            nl[(s + 2) % 3] = *(const float4*)(nb + (long)min(pd, D - 1) * HW + rowoff);
            vd[(s + 2) % 3] = (pd < D);
            pq[s % 3] = *(const float4*)(pgb + (long)(d0 + s) * HW + prowoff);
        }

        // ---- consume plane d0-1+s from slot s%3 ----
        const float4 cv = nl[s % 3];
        const bool vv = vd[s % 3] && hv;
        float nvv[4];
        nvv[0] = vv ? cv.x : NEG_INF;
        nvv[1] = vv ? cv.y : NEG_INF;
        nvv[2] = vv ? cv.z : NEG_INF;
        nvv[3] = vv ? cv.w : NEG_INF;

        // ---- in-row 3-wide max ----
        float le = __shfl(nvv[3], lane - 1);
        float re = __shfl(nvv[0], lane + 1);
        le = (q == 0)      ? NEG_INF : le;
        re = (q == LR - 1) ? NEG_INF : re;
        float rm[4];
        rm[0] = fmaxf(le,     fmaxf(nvv[0], nvv[1]));
        rm[1] = fmaxf(nvv[0], fmaxf(nvv[1], nvv[2]));
        rm[2] = fmaxf(nvv[1], fmaxf(nvv[2], nvv[3]));
        rm[3] = fmaxf(nvv[2], fmaxf(nvv[3], re));

        // ---- cross-row: group r needs rows r+1, r+2 and center row r+1 ----
        float rmA[4], rmB[4], ctr[4];
#pragma unroll
        for (int i = 0; i < 4; ++i) {
            rmA[i] = __shfl(rm[i],  lane + LR);
            rmB[i] = __shfl(rm[i],  lane + 2 * LR);
            ctr[i] = __shfl(nvv[i], lane + LR);
        }

        // ---- 3-deep d-window + emit (center plane d0+s-2) ----
        const float4 gp = pq[(s + 1) % 3];   // == (s-2)%3 for s>=2
        const float pgv[4] = {gp.x, gp.y, gp.z, gp.w};
#pragma unroll
        for (int i = 0; i < 4; ++i) {
            float hw2 = fmaxf(rm[i], fmaxf(rmA[i], rmB[i]));
            if (s >= 2 && g < NR && pgv[i] == -1.0f) {
                float mp = fmaxf(vm0[i], fmaxf(vm1[i], hw2));
                if (mp == cc1[i]) {
                    float pn = __expf(-cc1[i]);
                    float wn = (1.f - pn) * (1.f - pn);
                    loss += cc1[i] * wn;
                    cnt  += wn;
                }
            }
            vm0[i] = vm1[i]; vm1[i] = hw2; cc1[i] = ctr[i];
        }
    }

#pragma unroll
    for (int off = 32; off > 0; off >>= 1) {
        loss += __shfl_down(loss, off);
        cnt  += __shfl_down(cnt, off);
    }
    if (lane == 0) slot[uid] = make_float2(loss, cnt);
}

// ---------------------------------------------------------------------------
// Positive gathers: 8 waves per level, 1 item per lane (B*P = 512).
// ---------------------------------------------------------------------------
__device__ void pos_wave8(int sub, int lane,
                          const float* __restrict__ logit,
                          const float* __restrict__ prob_gt,
                          const int* __restrict__ coord,
                          const float* __restrict__ wcls,
                          float2* __restrict__ slot,
                          int D, int H, int W) {
    const int A = 3, P = 128;
    const long S = (long)D * H * W;
    const int i = sub * 64 + lane;
    const int b = i / P;
    const int* c = coord + (long)i * 4;
    const int a = c[0];
    float loss = 0.f, cnt = 0.f;
    if (a > -1) {
        const int d = c[1], h = c[2], w = c[3];
        const long s = ((long)d * H + h) * W + w;
        const int cls = (int)prob_gt[((long)b * A + a) * S + s];
        const float* lp = logit + ((long)b * 3 * A + a) * S + s;
        float l0 = lp[0];
        float l1 = lp[(long)A * S];
        float l2 = lp[2L * A * S];
        float m = fmaxf(l0, fmaxf(l1, l2));
        float e0 = __expf(l0 - m);
        float e1 = __expf(l1 - m);
        float e2 = __expf(l2 - m);
        float lsum = __logf(e0 + e1 + e2);
        float lc = (cls == 0) ? l0 : ((cls == 1) ? l1 : l2);
        float lpc = (lc - m) - lsum;
        float pt = __expf(lpc);
        float wp = (1.f - pt) * (1.f - pt) * wcls[cls];
        loss = (-lpc) * wp;
        cnt = wp;
    }
#pragma unroll
    for (int off = 32; off > 0; off >>= 1) {
        loss += __shfl_down(loss, off);
        cnt  += __shfl_down(cnt, off);
    }
    if (lane == 0) *slot = make_float2(loss, cnt);
}

// ---------------------------------------------------------------------------
// Pass 2 work split:
//   L0: NR=2, TD=8 -> 12*32*8 = 3072 waves ; L1: NR=4, TD=8 -> 12*8*4 = 384
//   pos: 16 waves.  Total 3472 waves -> 868 blocks.
// ---------------------------------------------------------------------------
#define NW0 3072
#define NW1 384
#define NWP 16
#define NSLOT_NEG (NW0 + NW1)
#define TOTAL_WAVES (NW0 + NW1 + NWP)

__global__ __launch_bounds__(256)
void nms_pass(const float* __restrict__ nllws,
              const float* __restrict__ logit0,
              const float* __restrict__ logit1,
              const float* __restrict__ pg0,
              const float* __restrict__ pg1,
              const int* __restrict__ coord0,
              const int* __restrict__ coord1,
              const float* __restrict__ wcls,
              float2* __restrict__ slots) {
    const int gw = blockIdx.x * 4 + (threadIdx.x >> 6);
    const int lane = threadIdx.x & 63;
    if (gw < NW0) {
        nms_strip<64, 2, 8, 64, 64>(gw, lane, nllws, pg0, slots);
    } else if (gw < NW0 + NW1) {
        nms_strip<32, 4, 8, 32, 32>(gw - NW0, lane, nllws + N0, pg1, slots + NW0);
    } else if (gw < NW0 + NW1 + 8) {
        const int sub = gw - NW0 - NW1;
        pos_wave8(sub, lane, logit0, pg0, coord0, wcls,
                  slots + NSLOT_NEG + sub, 64, 64, 64);
    } else {
        const int sub = gw - NW0 - NW1 - 8;
        pos_wave8(sub, lane, logit1, pg1, coord1, wcls,
                  slots + NSLOT_NEG + 8 + sub, 32, 32, 32);
    }
}

// ---------------------------------------------------------------------------
// Final reduction.
// ---------------------------------------------------------------------------
__global__ __launch_bounds__(1024)
void final_reduce(const float2* __restrict__ slots, float* __restrict__ out) {
    float ln = 0.f, cn = 0.f, lp = 0.f, cp = 0.f;
    for (int i = threadIdx.x; i < NSLOT_NEG; i += 1024) {
        float2 v = slots[i]; ln += v.x; cn += v.y;
    }
    if (threadIdx.x < NWP) {
        float2 v = slots[NSLOT_NEG + threadIdx.x]; lp = v.x; cp = v.y;
    }
#pragma unroll
    for (int off = 32; off > 0; off >>= 1) {
        ln += __shfl_down(ln, off); cn += __shfl_down(cn, off);
        lp += __shfl_down(lp, off); cp += __shfl_down(cp, off);
    }
    __shared__ float s[16][4];
    const int wv = threadIdx.x >> 6;
    if ((threadIdx.x & 63) == 0) {
        s[wv][0] = ln; s[wv][1] = cn; s[wv][2] = lp; s[wv][3] = cp;
    }
    __syncthreads();
    if (threadIdx.x == 0) {
        float a = 0.f, b = 0.f, c = 0.f, d = 0.f;
#pragma unroll
        for (int i = 0; i < 16; ++i) {
            a += s[i][0]; b += s[i][1]; c += s[i][2]; d += s[i][3];
        }
        out[0] = c;   // loss_pos
        out[1] = a;   // loss_neg
        out[2] = d;   // count_pos
        out[3] = b;   // count_neg
    }
}

extern "C" void kernel_launch(void* const* d_in, const int* in_sizes, int n_in,
                              void* d_out, int out_size, void* d_ws, size_t ws_size,
                              hipStream_t stream) {
    const float* logit0   = (const float*)d_in[0];
    const float* logit1   = (const float*)d_in[1];
    const float* prob_gt0 = (const float*)d_in[2];
    const float* prob_gt1 = (const float*)d_in[3];
    const int*   coord0   = (const int*)d_in[4];
    const int*   coord1   = (const int*)d_in[5];
    const float* wcls     = (const float*)d_in[6];
    float* out = (float*)d_out;

    float*  nllws = (float*)d_ws;                          // N0+N1 floats
    float2* slots = (float2*)(nllws + N0 + N1);            // 3472 float2

    nll_pass<<<P1_BLOCKS, 256, 0, stream>>>(logit0, logit1, nllws);
    nms_pass<<<TOTAL_WAVES / 4, 256, 0, stream>>>(
        nllws, logit0, logit1, prob_gt0, prob_gt1, coord0, coord1, wcls, slots);
    final_reduce<<<1, 1024, 0, stream>>>(slots, out);
}